// Round 10
// baseline (129.832 us; speedup 1.0000x reference)
//
#include <hip/hip_runtime.h>
#include <hip/hip_bf16.h>
#include <hip/hip_fp16.h>

typedef __attribute__((ext_vector_type(4))) float f32x4;
typedef __attribute__((ext_vector_type(8))) _Float16 f16x8;
typedef __attribute__((ext_vector_type(8))) unsigned short u16x8;

__device__ __forceinline__ unsigned short f2h(float f) {
    _Float16 h = (_Float16)f;
    return __builtin_bit_cast(unsigned short, h);
}

#define GLOAD_LDS16(gp, lp) __builtin_amdgcn_global_load_lds( \
    (const __attribute__((address_space(1))) void*)(gp), \
    (__attribute__((address_space(3))) void*)(lp), 16, 0, 0)
#define PRIO1() __builtin_amdgcn_s_setprio(1)
#define PRIO0() __builtin_amdgcn_s_setprio(0)

// ---------------- fp32 -> fp16 elementwise convert (vectorized) ----------------
__global__ void cvt_kernel(const float* __restrict__ in, ushort* __restrict__ out, int n4) {
    int stride = gridDim.x * blockDim.x;
    for (int i = blockIdx.x * blockDim.x + threadIdx.x; i < n4; i += stride) {
        float4 v = ((const float4*)in)[i];
        ushort4 o;
        o.x = f2h(v.x); o.y = f2h(v.y); o.z = f2h(v.z); o.w = f2h(v.w);
        ((ushort4*)out)[i] = o;
    }
}

// ---------------- transpose + convert Wk/Wv (for the KV projection GEMM) ----------------
__global__ void transpose_cvt2(const float* __restrict__ Wk, const float* __restrict__ Wv,
                               ushort* __restrict__ WkvT) {
    __shared__ float tile[32][33];
    const int z = blockIdx.z;
    const float* src = z ? Wv : Wk;
    ushort* dst = WkvT + (size_t)z * 640 * 768;
    const int R = 768, C = 640;
    int tx = threadIdx.x, ty = threadIdx.y;
    int c = blockIdx.x * 32 + tx;
    int r0 = blockIdx.y * 32;
#pragma unroll
    for (int i = ty; i < 32; i += 8) {
        int r = r0 + i;
        tile[i][tx] = (r < R && c < C) ? src[(size_t)r * C + c] : 0.f;
    }
    __syncthreads();
    int rr = r0 + tx;
    int c0 = blockIdx.x * 32;
#pragma unroll
    for (int i = ty; i < 32; i += 8) {
        int cc = c0 + i;
        if (cc < C && rr < R) dst[(size_t)cc * R + rr] = f2h(tile[tx][i]);
    }
}

// ---------------- pack W (fp32 [640 k][640 n]) into fragment-linear f16 ----------------
// WF frag g = ((h*10 + kt)*10 + (ni*2+kk))*64 + lane, 8 elems:
//   elem e = f16( W[(kt*64 + kk*32 + (lane>>4)*8 + e)*640 + h*80 + ni*16 + (lane&15)] )
__global__ void pack_wfrag(const float* __restrict__ W, ushort* __restrict__ WF) {
    int g = blockIdx.x * 256 + threadIdx.x;   // 0 .. 51199
    if (g >= 51200) return;
    int lane = g & 63;
    int fi = (g >> 6) % 10;
    int kt = ((g >> 6) / 10) % 10;
    int h  = (g >> 6) / 100;
    int ni = fi >> 1, kk = fi & 1;
    int n  = h * 80 + ni * 16 + (lane & 15);
    int k0 = kt * 64 + kk * 32 + (lane >> 4) * 8;
    u16x8 o;
#pragma unroll
    for (int e = 0; e < 8; ++e) o[e] = f2h(W[(size_t)(k0 + e) * 640 + n]);
    *(u16x8*)&WF[(size_t)g * 8] = o;
}

// ---------------- pack K,V fragments from KVb ----------------
__global__ void pack_kvfrag(const ushort* __restrict__ KVb,
                            ushort* __restrict__ KF, ushort* __restrict__ VF) {
    int g = blockIdx.x * 256 + threadIdx.x;   // 0 .. 61439
    if (g >= 61440) return;
    int lane = g & 63;
    int fi = (g >> 6) % 15;
    int bh = (g >> 6) / 15;
    int b = bh >> 3, h = bh & 7;
    int ni = fi / 3, kk = fi % 3;
    int l15 = lane & 15, lhi = lane >> 4;
    int sr = ni * 16 + l15; if (sr > 76) sr = 76;
    int d0 = kk * 32 + lhi * 8;
    u16x8 ko, vo;
#pragma unroll
    for (int e = 0; e < 8; ++e)
        ko[e] = KVb[((size_t)b * 77 + sr) * 1280 + h * 80 + d0 + e];
    int dv = ni * 16 + l15;            // < 80 always
    int s0 = kk * 32 + lhi * 8;
#pragma unroll
    for (int e = 0; e < 8; ++e) {
        int s = s0 + e;
        vo[e] = (s < 77) ? KVb[((size_t)b * 77 + s) * 1280 + 640 + h * 80 + dv] : (ushort)0;
    }
    *(u16x8*)&KF[(size_t)g * 8] = ko;
    *(u16x8*)&VF[(size_t)g * 8] = vo;
}

// ---------------- 128x128 GEMM (for the tiny KV projection) ----------------
template<int OUT_F16, int HAS_BIAS>
__global__ __launch_bounds__(256) void gemm_bt(
    const ushort* __restrict__ A, const ushort* __restrict__ Bt,
    void* __restrict__ C, const float* __restrict__ bias,
    int M, int N, int K)
{
    __shared__ ushort As[128 * 64];
    __shared__ ushort Bs[128 * 64];
    const int tid = threadIdx.x;
    const int lane = tid & 63;
    const int w = tid >> 6;
    const int wr = (w >> 1) * 64, wc = (w & 1) * 64;
    const int m0 = blockIdx.x * 128, n0 = blockIdx.y * 128;
    const int l15 = lane & 15, lhi = lane >> 4;

    f32x4 acc[4][4] = {};

    for (int k0 = 0; k0 < K; k0 += 64) {
        __syncthreads();
#pragma unroll
        for (int i = 0; i < 4; ++i) {
            int c = i * 256 + tid;
            int m = m0 + (c >> 3);
            if (m > M - 1) m = M - 1;
            GLOAD_LDS16(A + (size_t)m * K + k0 + (c & 7) * 8, &As[c * 8]);
        }
#pragma unroll
        for (int i = 0; i < 4; ++i) {
            int c = i * 256 + tid;
            GLOAD_LDS16(Bt + (size_t)(n0 + (c >> 3)) * K + k0 + (c & 7) * 8, &Bs[c * 8]);
        }
        __syncthreads();
#pragma unroll
        for (int kk = 0; kk < 2; ++kk) {
            f16x8 af[4], bfr[4];
#pragma unroll
            for (int mi = 0; mi < 4; ++mi)
                af[mi] = *(const f16x8*)&As[(wr + mi * 16 + l15) * 64 + kk * 32 + lhi * 8];
#pragma unroll
            for (int ni = 0; ni < 4; ++ni)
                bfr[ni] = *(const f16x8*)&Bs[(wc + ni * 16 + l15) * 64 + kk * 32 + lhi * 8];
#pragma unroll
            for (int mi = 0; mi < 4; ++mi)
#pragma unroll
                for (int ni = 0; ni < 4; ++ni)
                    acc[mi][ni] = __builtin_amdgcn_mfma_f32_16x16x32_f16(
                        af[mi], bfr[ni], acc[mi][ni], 0, 0, 0);
        }
    }

#pragma unroll
    for (int mi = 0; mi < 4; ++mi)
#pragma unroll
        for (int ni = 0; ni < 4; ++ni)
#pragma unroll
            for (int r = 0; r < 4; ++r) {
                int row = m0 + wr + mi * 16 + lhi * 4 + r;
                int col = n0 + wc + ni * 16 + l15;
                if (row < M) {
                    float v = acc[mi][ni][r];
                    if (HAS_BIAS) v += bias[col];
                    if (OUT_F16) ((ushort*)C)[(size_t)row * N + col] = f2h(v);
                    else         ((float*)C)[(size_t)row * N + col] = v;
                }
            }
}

// ================= fused: tokens->Q-proj->attention->O-proj->out =================
// R10: 32-row blocks, grid (128 tt, 8 b) = 1024 blocks; 512 thr = 8 waves, wave = head.
// GOAL: VGPR+AGPR total <= 128/wave so TWO blocks co-reside (16 waves/CU).
//   Unified-regfile theory from R4-R9: occupancy gates on VGPR+AGPR sum, not the
//   reported VGPR_Count. acc [2][5]=40; B-frags single-buffered kk-granularity
//   (named PE/PO, 40 live); attn frags 1-deep prefetch. LDS 40 KiB exactly:
//   toks [32][640] swz @0  ->  Q/P per-wave [32][80] @ w*2560 (alias)  ->  ctxall (alias).
// Cost accepted: W-frag L2 traffic doubles vs 64-row (overlappable stream).
__global__ __launch_bounds__(512, 2) void fused_attn(
    const float* __restrict__ tokens, const ushort* __restrict__ WqF,
    const ushort* __restrict__ KF, const ushort* __restrict__ VF,
    const ushort* __restrict__ WoF, const float* __restrict__ bo,
    float* __restrict__ out)
{
    __shared__ __align__(16) ushort lds[20480];   // 40 KiB
    const int tid = threadIdx.x;
    const int lane = tid & 63;
    const int w = tid >> 6;
    const int l15 = lane & 15, lhi = lane >> 4;
    const int tt = blockIdx.x, b = blockIdx.y;
    const size_t rowbase = (size_t)b * 4096 + (size_t)tt * 32;

    // fragment-linear bases (ushort units; one frag = 512 ushorts = 64 lanes x 8)
    const ushort* WqFb = WqF + (size_t)w * 10 * 5120;
    const ushort* WoFb = WoF + (size_t)w * 10 * 5120;
    const ushort* KFb  = KF + (size_t)(b * 8 + w) * 15 * 512;
    const ushort* VFb  = VF + (size_t)(b * 8 + w) * 15 * 512;

    // ---- stage token tile [32][640] f16, swizzled; 16 threads/row, 5 chunks each ----
    {
        const int srow = tid >> 4;        // 0..31
        const int c16  = tid & 15;
        const float* tbase = tokens + (rowbase + srow) * 640 + c16 * 8;
        float4 sA[5], sB[5];
#pragma unroll
        for (int i = 0; i < 5; ++i) {
            sA[i] = ((const float4*)(tbase + i * 128))[0];
            sB[i] = ((const float4*)(tbase + i * 128))[1];
        }
#pragma unroll
        for (int i = 0; i < 5; ++i) {
            int slot = i * 16 + c16;
            int phys = (slot & ~7) | ((slot ^ srow) & 7);
            u16x8 o;
            o[0]=f2h(sA[i].x); o[1]=f2h(sA[i].y); o[2]=f2h(sA[i].z); o[3]=f2h(sA[i].w);
            o[4]=f2h(sB[i].x); o[5]=f2h(sB[i].y); o[6]=f2h(sB[i].z); o[7]=f2h(sB[i].w);
            *(u16x8*)&lds[srow * 640 + phys * 8] = o;
        }
    }
    f16x8 PE[5], PO[5];
#pragma unroll
    for (int f = 0; f < 5; ++f)
        PE[f] = *(const f16x8*)(WqFb + (f * 2) * 512 + lane * 8);
    __syncthreads();                      // bar1: token tile ready

    // ---- Q projection (barrier-free): qacc[2][5] += toks(32x640) @ Wq ----
    f32x4 qacc[2][5] = {};
#define GHALF(ACC, PC, PN, WB, KT, KK, NKT, NKK, DOPF) do { \
    if (DOPF) { \
        _Pragma("unroll") for (int f = 0; f < 5; ++f) \
            (PN)[f] = *(const f16x8*)((WB) + (size_t)(NKT) * 5120 + (f * 2 + (NKK)) * 512 + lane * 8); \
    } \
    f16x8 af[2]; \
    _Pragma("unroll") for (int mi = 0; mi < 2; ++mi) { \
        int row_ = mi * 16 + l15; \
        af[mi] = *(const f16x8*)&lds[row_ * 640 + ((KT) * 8 + (((KK) * 4 + lhi) ^ (row_ & 7))) * 8]; \
    } \
    PRIO1(); \
    _Pragma("unroll") for (int mi = 0; mi < 2; ++mi) \
    _Pragma("unroll") for (int ni = 0; ni < 5; ++ni) \
        (ACC)[mi][ni] = __builtin_amdgcn_mfma_f32_16x16x32_f16(af[mi], (PC)[ni], (ACC)[mi][ni], 0, 0, 0); \
    PRIO0(); \
} while (0)

    for (int kt = 0; kt < 10; ++kt) {
        GHALF(qacc, PE, PO, WqFb, kt, 0, kt, 1, 1);
        GHALF(qacc, PO, PE, WqFb, kt, 1, kt + 1, 0, kt < 9);
    }
    __syncthreads();                      // bar2: toks dead everywhere

    // ---- write Q f16 into per-wave [32][80] region (aliases toks) ----
    const int qoff = w * 2560;
#pragma unroll
    for (int mi = 0; mi < 2; ++mi)
#pragma unroll
        for (int ni = 0; ni < 5; ++ni)
#pragma unroll
            for (int r = 0; r < 4; ++r)
                lds[qoff + (mi*16 + lhi*4 + r)*80 + ni*16 + l15] = f2h(qacc[mi][ni][r]);
    __builtin_amdgcn_sched_barrier(0);

    const f16x8 zf = {};
    // ---- S = Q K^T (packed K frags, 1-deep kk prefetch) ----
    f32x4 sa[2][5] = {};
#define ATT_KK(ACC, PC, PN, FB, KK, NKK, DOPF) do { \
    if (DOPF) { \
        _Pragma("unroll") for (int f = 0; f < 5; ++f) \
            (PN)[f] = *(const f16x8*)((FB) + (f * 3 + (NKK)) * 512 + lane * 8); \
    } \
    f16x8 aq[2]; \
    const int kcol = ((KK) < 2) ? ((KK)*32 + lhi*8) : (64 + (lhi & 1)*8); \
    _Pragma("unroll") for (int mi = 0; mi < 2; ++mi) { \
        aq[mi] = *(const f16x8*)&lds[qoff + (mi*16 + l15)*80 + kcol]; \
        if ((KK) == 2 && lhi >= 2) aq[mi] = zf; \
    } \
    PRIO1(); \
    _Pragma("unroll") for (int mi = 0; mi < 2; ++mi) \
    _Pragma("unroll") for (int ni = 0; ni < 5; ++ni) \
        (ACC)[mi][ni] = __builtin_amdgcn_mfma_f32_16x16x32_f16(aq[mi], (PC)[ni], (ACC)[mi][ni], 0, 0, 0); \
    PRIO0(); \
} while (0)

#pragma unroll
    for (int f = 0; f < 5; ++f)
        PE[f] = *(const f16x8*)(KFb + (f * 3) * 512 + lane * 8);
    ATT_KK(sa, PE, PO, KFb, 0, 1, 1);
    ATT_KK(sa, PO, PE, KFb, 1, 2, 1);
    ATT_KK(sa, PE, PO, KFb, 2, 0, 0);
    __builtin_amdgcn_sched_barrier(0);

    // ---- softmax over s (77 valid), P f16 back into the same region ----
    const float sc = 0.11180339887498949f;   // 1/sqrt(80)
#pragma unroll
    for (int mi = 0; mi < 2; ++mi)
#pragma unroll
        for (int r = 0; r < 4; ++r) {
            float v0 = sa[mi][0][r]*sc, v1 = sa[mi][1][r]*sc, v2 = sa[mi][2][r]*sc,
                  v3 = sa[mi][3][r]*sc, v4 = sa[mi][4][r]*sc;
            bool ok4 = l15 < 13;             // col 64+l15 < 77
            float mx = fmaxf(fmaxf(v0, v1), fmaxf(v2, v3));
            if (ok4) mx = fmaxf(mx, v4);
#pragma unroll
            for (int off = 1; off < 16; off <<= 1) mx = fmaxf(mx, __shfl_xor(mx, off, 16));
            float p0 = __expf(v0-mx), p1 = __expf(v1-mx), p2 = __expf(v2-mx), p3 = __expf(v3-mx);
            float p4 = ok4 ? __expf(v4-mx) : 0.f;
            float sm = p0+p1+p2+p3+p4;
#pragma unroll
            for (int off = 1; off < 16; off <<= 1) sm += __shfl_xor(sm, off, 16);
            float inv = 1.f / sm;
            int row = mi*16 + lhi*4 + r;
            lds[qoff + row*80 + 0*16 + l15] = f2h(p0*inv);
            lds[qoff + row*80 + 1*16 + l15] = f2h(p1*inv);
            lds[qoff + row*80 + 2*16 + l15] = f2h(p2*inv);
            lds[qoff + row*80 + 3*16 + l15] = f2h(p3*inv);
            lds[qoff + row*80 + 4*16 + l15] = f2h(p4*inv);
        }
    __builtin_amdgcn_sched_barrier(0);

    // ---- O = P V (packed V frags; s>=77 cols are true zeros) ----
    f32x4 oa[2][5] = {};
#pragma unroll
    for (int f = 0; f < 5; ++f)
        PE[f] = *(const f16x8*)(VFb + (f * 3) * 512 + lane * 8);
    ATT_KK(oa, PE, PO, VFb, 0, 1, 1);
    ATT_KK(oa, PO, PE, VFb, 1, 2, 1);
    ATT_KK(oa, PE, PO, VFb, 2, 0, 0);
#undef ATT_KK
    __syncthreads();                      // bar3: Q/P regions dead

    // ---- ctxall [32][640] swizzled = concat of heads ----
#pragma unroll
    for (int mi = 0; mi < 2; ++mi)
#pragma unroll
        for (int ni = 0; ni < 5; ++ni)
#pragma unroll
            for (int r = 0; r < 4; ++r) {
                int row = mi*16 + lhi*4 + r;
                int col = w*80 + ni*16 + l15;
                int slot = col >> 3;
                int phys = (slot & ~7) | ((slot ^ row) & 7);
                lds[row*640 + phys*8 + (col & 7)] = f2h(oa[mi][ni][r]);
            }
    __syncthreads();                      // bar4: ctxall ready

    // ---- O projection (barrier-free): out = ctxall @ Wo + bo ----
    f32x4 cacc[2][5] = {};
#pragma unroll
    for (int f = 0; f < 5; ++f)
        PE[f] = *(const f16x8*)(WoFb + (f * 2) * 512 + lane * 8);
    for (int kt = 0; kt < 10; ++kt) {
        GHALF(cacc, PE, PO, WoFb, kt, 0, kt, 1, 1);
        GHALF(cacc, PO, PE, WoFb, kt, 1, kt + 1, 0, kt < 9);
    }
#undef GHALF

    // ---- epilogue: f32 out + bias ----
#pragma unroll
    for (int ni = 0; ni < 5; ++ni) {
        int col = w*80 + ni*16 + l15;
        float bvl = bo[col];
#pragma unroll
        for (int mi = 0; mi < 2; ++mi)
#pragma unroll
            for (int r = 0; r < 4; ++r)
                out[(rowbase + mi*16 + lhi*4 + r) * 640 + col] = cacc[mi][ni][r] + bvl;
    }
}

extern "C" void kernel_launch(void* const* d_in, const int* in_sizes, int n_in,
                              void* d_out, int out_size, void* d_ws, size_t ws_size,
                              hipStream_t stream) {
    (void)in_sizes; (void)n_in; (void)out_size; (void)ws_size;
    const float* tokens  = (const float*)d_in[0];
    const float* context = (const float*)d_in[1];
    const float* Wq = (const float*)d_in[2];
    const float* Wk = (const float*)d_in[3];
    const float* Wv = (const float*)d_in[4];
    const float* Wo = (const float*)d_in[5];
    const float* bo = (const float*)d_in[6];
    float* out = (float*)d_out;

    ushort* ws   = (ushort*)d_ws;
    ushort* ctx16 = ws;                                   // 616*768
    ushort* WkvT = ctx16 + (size_t)616 * 768;             // 1280*768
    ushort* KVb  = WkvT + (size_t)1280 * 768;             // 616*1280
    ushort* WqF  = KVb  + (size_t)616 * 1280;             // 640*640
    ushort* WoF  = WqF  + (size_t)640 * 640;              // 640*640
    ushort* KF   = WoF  + (size_t)640 * 640;              // 61440*8
    ushort* VF   = KF   + (size_t)61440 * 8;              // 61440*8

    cvt_kernel<<<462, 256, 0, stream>>>(context, ctx16, 616 * 768 / 4);
    transpose_cvt2<<<dim3(20, 24, 2), dim3(32, 8), 0, stream>>>(Wk, Wv, WkvT);
    pack_wfrag<<<200, 256, 0, stream>>>(Wq, WqF);
    pack_wfrag<<<200, 256, 0, stream>>>(Wo, WoF);
    gemm_bt<1, 0><<<dim3(5, 10), 256, 0, stream>>>(ctx16, WkvT, KVb, nullptr, 616, 1280, 768);
    pack_kvfrag<<<240, 256, 0, stream>>>(KVb, KF, VF);
    fused_attn<<<dim3(128, 8), 512, 0, stream>>>(tokens, WqF, KF, VF, WoF, bo, out);
}

// Round 11
// 118.467 us; speedup vs baseline: 1.0959x; 1.0959x over previous
//
#include <hip/hip_runtime.h>
#include <hip/hip_bf16.h>
#include <hip/hip_fp16.h>

typedef __attribute__((ext_vector_type(4))) float f32x4;
typedef __attribute__((ext_vector_type(8))) _Float16 f16x8;
typedef __attribute__((ext_vector_type(8))) unsigned short u16x8;

__device__ __forceinline__ unsigned short f2h(float f) {
    _Float16 h = (_Float16)f;
    return __builtin_bit_cast(unsigned short, h);
}

#define GLOAD_LDS16(gp, lp) __builtin_amdgcn_global_load_lds( \
    (const __attribute__((address_space(1))) void*)(gp), \
    (__attribute__((address_space(3))) void*)(lp), 16, 0, 0)
#define PRIO1() __builtin_amdgcn_s_setprio(1)
#define PRIO0() __builtin_amdgcn_s_setprio(0)

// ---------------- fp32 -> fp16 elementwise convert (vectorized) ----------------
__global__ void cvt_kernel(const float* __restrict__ in, ushort* __restrict__ out, int n4) {
    int stride = gridDim.x * blockDim.x;
    for (int i = blockIdx.x * blockDim.x + threadIdx.x; i < n4; i += stride) {
        float4 v = ((const float4*)in)[i];
        ushort4 o;
        o.x = f2h(v.x); o.y = f2h(v.y); o.z = f2h(v.z); o.w = f2h(v.w);
        ((ushort4*)out)[i] = o;
    }
}

// ---------------- transpose + convert Wk/Wv (for the KV projection GEMM) ----------------
__global__ void transpose_cvt2(const float* __restrict__ Wk, const float* __restrict__ Wv,
                               ushort* __restrict__ WkvT) {
    __shared__ float tile[32][33];
    const int z = blockIdx.z;
    const float* src = z ? Wv : Wk;
    ushort* dst = WkvT + (size_t)z * 640 * 768;
    const int R = 768, C = 640;
    int tx = threadIdx.x, ty = threadIdx.y;
    int c = blockIdx.x * 32 + tx;
    int r0 = blockIdx.y * 32;
#pragma unroll
    for (int i = ty; i < 32; i += 8) {
        int r = r0 + i;
        tile[i][tx] = (r < R && c < C) ? src[(size_t)r * C + c] : 0.f;
    }
    __syncthreads();
    int rr = r0 + tx;
    int c0 = blockIdx.x * 32;
#pragma unroll
    for (int i = ty; i < 32; i += 8) {
        int cc = c0 + i;
        if (cc < C && rr < R) dst[(size_t)cc * R + rr] = f2h(tile[tx][i]);
    }
}

// ---------------- pack W (fp32 [640 k][640 n]) into fragment-linear f16 ----------------
__global__ void pack_wfrag(const float* __restrict__ W, ushort* __restrict__ WF) {
    int g = blockIdx.x * 256 + threadIdx.x;   // 0 .. 51199
    if (g >= 51200) return;
    int lane = g & 63;
    int fi = (g >> 6) % 10;
    int kt = ((g >> 6) / 10) % 10;
    int h  = (g >> 6) / 100;
    int ni = fi >> 1, kk = fi & 1;
    int n  = h * 80 + ni * 16 + (lane & 15);
    int k0 = kt * 64 + kk * 32 + (lane >> 4) * 8;
    u16x8 o;
#pragma unroll
    for (int e = 0; e < 8; ++e) o[e] = f2h(W[(size_t)(k0 + e) * 640 + n]);
    *(u16x8*)&WF[(size_t)g * 8] = o;
}

// ---------------- pack K,V fragments from KVb ----------------
__global__ void pack_kvfrag(const ushort* __restrict__ KVb,
                            ushort* __restrict__ KF, ushort* __restrict__ VF) {
    int g = blockIdx.x * 256 + threadIdx.x;   // 0 .. 61439
    if (g >= 61440) return;
    int lane = g & 63;
    int fi = (g >> 6) % 15;
    int bh = (g >> 6) / 15;
    int b = bh >> 3, h = bh & 7;
    int ni = fi / 3, kk = fi % 3;
    int l15 = lane & 15, lhi = lane >> 4;
    int sr = ni * 16 + l15; if (sr > 76) sr = 76;
    int d0 = kk * 32 + lhi * 8;
    u16x8 ko, vo;
#pragma unroll
    for (int e = 0; e < 8; ++e)
        ko[e] = KVb[((size_t)b * 77 + sr) * 1280 + h * 80 + d0 + e];
    int dv = ni * 16 + l15;            // < 80 always
    int s0 = kk * 32 + lhi * 8;
#pragma unroll
    for (int e = 0; e < 8; ++e) {
        int s = s0 + e;
        vo[e] = (s < 77) ? KVb[((size_t)b * 77 + s) * 1280 + 640 + h * 80 + dv] : (ushort)0;
    }
    *(u16x8*)&KF[(size_t)g * 8] = ko;
    *(u16x8*)&VF[(size_t)g * 8] = vo;
}

// ---------------- 128x128 GEMM (for the tiny KV projection) ----------------
template<int OUT_F16, int HAS_BIAS>
__global__ __launch_bounds__(256) void gemm_bt(
    const ushort* __restrict__ A, const ushort* __restrict__ Bt,
    void* __restrict__ C, const float* __restrict__ bias,
    int M, int N, int K)
{
    __shared__ ushort As[128 * 64];
    __shared__ ushort Bs[128 * 64];
    const int tid = threadIdx.x;
    const int lane = tid & 63;
    const int w = tid >> 6;
    const int wr = (w >> 1) * 64, wc = (w & 1) * 64;
    const int m0 = blockIdx.x * 128, n0 = blockIdx.y * 128;
    const int l15 = lane & 15, lhi = lane >> 4;

    f32x4 acc[4][4] = {};

    for (int k0 = 0; k0 < K; k0 += 64) {
        __syncthreads();
#pragma unroll
        for (int i = 0; i < 4; ++i) {
            int c = i * 256 + tid;
            int m = m0 + (c >> 3);
            if (m > M - 1) m = M - 1;
            GLOAD_LDS16(A + (size_t)m * K + k0 + (c & 7) * 8, &As[c * 8]);
        }
#pragma unroll
        for (int i = 0; i < 4; ++i) {
            int c = i * 256 + tid;
            GLOAD_LDS16(Bt + (size_t)(n0 + (c >> 3)) * K + k0 + (c & 7) * 8, &Bs[c * 8]);
        }
        __syncthreads();
#pragma unroll
        for (int kk = 0; kk < 2; ++kk) {
            f16x8 af[4], bfr[4];
#pragma unroll
            for (int mi = 0; mi < 4; ++mi)
                af[mi] = *(const f16x8*)&As[(wr + mi * 16 + l15) * 64 + kk * 32 + lhi * 8];
#pragma unroll
            for (int ni = 0; ni < 4; ++ni)
                bfr[ni] = *(const f16x8*)&Bs[(wc + ni * 16 + l15) * 64 + kk * 32 + lhi * 8];
#pragma unroll
            for (int mi = 0; mi < 4; ++mi)
#pragma unroll
                for (int ni = 0; ni < 4; ++ni)
                    acc[mi][ni] = __builtin_amdgcn_mfma_f32_16x16x32_f16(
                        af[mi], bfr[ni], acc[mi][ni], 0, 0, 0);
        }
    }

#pragma unroll
    for (int mi = 0; mi < 4; ++mi)
#pragma unroll
        for (int ni = 0; ni < 4; ++ni)
#pragma unroll
            for (int r = 0; r < 4; ++r) {
                int row = m0 + wr + mi * 16 + lhi * 4 + r;
                int col = n0 + wc + ni * 16 + l15;
                if (row < M) {
                    float v = acc[mi][ni][r];
                    if (HAS_BIAS) v += bias[col];
                    if (OUT_F16) ((ushort*)C)[(size_t)row * N + col] = f2h(v);
                    else         ((float*)C)[(size_t)row * N + col] = v;
                }
            }
}

// ================= fused: tokens->Q-proj->attention->O-proj->out =================
// R11: 128-row blocks, grid (32 tt, 8 b) = 256 blocks = exactly 1/CU.
//   Rationale (R8 vs R10 A/B): per-XCD L2 W-frag stream scales with block count
//   (1.8 MB/block). 64-row: ~24us/XCD; 32-row: ~48us (dur 103->115 despite 2x occ).
//   128-row halves it to ~12us. Registers: acc[8][5]=160 -> launch_bounds(512,1)
//   (cap 256 per calibrated 256/arg rule). Single-A-frag inner loop caps liveness.
// LDS 160 KiB: token dbuf [2][128][64] @0/8192 (per-kt staged, load-early/
//   write-after-barrier hides HBM under the 80-MFMA kt step); per-wave Q/P
//   [128][80] @ w*10240 (aliases dbuf after last kt barrier); ctxall [128][640]
//   swizzled @0 (aliases all, after PV barrier).
__global__ __launch_bounds__(512, 1) void fused_attn(
    const float* __restrict__ tokens, const ushort* __restrict__ WqF,
    const ushort* __restrict__ KF, const ushort* __restrict__ VF,
    const ushort* __restrict__ WoF, const float* __restrict__ bo,
    float* __restrict__ out)
{
    __shared__ __align__(16) ushort lds[81920];   // 160 KiB
    const int tid = threadIdx.x;
    const int lane = tid & 63;
    const int w = tid >> 6;
    const int l15 = lane & 15, lhi = lane >> 4;
    const int tt = blockIdx.x, b = blockIdx.y;
    const size_t rowbase = (size_t)b * 4096 + (size_t)tt * 128;

    // fragment-linear bases (ushort units; one frag = 512 ushorts = 64 lanes x 8)
    const ushort* WqFb = WqF + (size_t)w * 10 * 5120;
    const ushort* WoFb = WoF + (size_t)w * 10 * 5120;
    const ushort* KFb  = KF + (size_t)(b * 8 + w) * 15 * 512;
    const ushort* VFb  = VF + (size_t)(b * 8 + w) * 15 * 512;

    // staging map: entries e = tid and tid+512 of 1024 (row = e>>3, 16B slot = e&7)
    const int r0s = tid >> 3;             // 0..63
    const int r1s = r0s + 64;             // 64..127
    const int s0s = tid & 7;
    const int d0s = r0s * 64 + (s0s ^ (r0s & 7)) * 8;   // swizzled dest (ushorts)
    const int d1s = r1s * 64 + (s0s ^ (r1s & 7)) * 8;

#define STAGE_LOAD(C, A0, B0, A1, B1) do { \
    const float* p0_ = tokens + (rowbase + r0s) * 640 + (C) * 64 + s0s * 8; \
    const float* p1_ = tokens + (rowbase + r1s) * 640 + (C) * 64 + s0s * 8; \
    A0 = ((const float4*)p0_)[0]; B0 = ((const float4*)p0_)[1]; \
    A1 = ((const float4*)p1_)[0]; B1 = ((const float4*)p1_)[1]; \
} while (0)
#define STAGE_WRITE(BUF, A0, B0, A1, B1) do { \
    u16x8 o0_, o1_; \
    o0_[0]=f2h(A0.x); o0_[1]=f2h(A0.y); o0_[2]=f2h(A0.z); o0_[3]=f2h(A0.w); \
    o0_[4]=f2h(B0.x); o0_[5]=f2h(B0.y); o0_[6]=f2h(B0.z); o0_[7]=f2h(B0.w); \
    o1_[0]=f2h(A1.x); o1_[1]=f2h(A1.y); o1_[2]=f2h(A1.z); o1_[3]=f2h(A1.w); \
    o1_[4]=f2h(B1.x); o1_[5]=f2h(B1.y); o1_[6]=f2h(B1.z); o1_[7]=f2h(B1.w); \
    *(u16x8*)&lds[(BUF) * 8192 + d0s] = o0_; \
    *(u16x8*)&lds[(BUF) * 8192 + d1s] = o1_; \
} while (0)

    // ---- prologue: stage chunks 0,1 ----
    {
        float4 a0, b0, a1, b1, c0, d0, c1, d1;
        STAGE_LOAD(0, a0, b0, a1, b1);
        STAGE_LOAD(1, c0, d0, c1, d1);
        STAGE_WRITE(0, a0, b0, a1, b1);
        STAGE_WRITE(1, c0, d0, c1, d1);
    }
    f16x8 PE[5], PO[5];
#pragma unroll
    for (int f = 0; f < 5; ++f)
        PE[f] = *(const f16x8*)(WqFb + (f * 2) * 512 + lane * 8);
    __syncthreads();

    // ---- Q projection: qacc[8][5] = toks(128x640) @ Wq[:, w*80..+80] ----
    f32x4 qacc[8][5] = {};
// one kk-half: optional prefetch of next half's 5 B-frags; 8 A-frags read singly
#define MHALF(ACC, PC, PN, WB, CURB, RSTR, SBASE, KK, NKT, NKK, DOPF) do { \
    if (DOPF) { \
        _Pragma("unroll") for (int f = 0; f < 5; ++f) \
            (PN)[f] = *(const f16x8*)((WB) + (size_t)(NKT) * 5120 + (f * 2 + (NKK)) * 512 + lane * 8); \
    } \
    PRIO1(); \
    _Pragma("unroll") for (int mi = 0; mi < 8; ++mi) { \
        int row_ = mi * 16 + l15; \
        f16x8 a_ = *(const f16x8*)&lds[(CURB) + row_ * (RSTR) + ((SBASE) + (((KK) * 4 + lhi) ^ (row_ & 7))) * 8]; \
        _Pragma("unroll") for (int ni = 0; ni < 5; ++ni) \
            (ACC)[mi][ni] = __builtin_amdgcn_mfma_f32_16x16x32_f16(a_, (PC)[ni], (ACC)[mi][ni], 0, 0, 0); \
    } \
    PRIO0(); \
} while (0)

    for (int kt = 0; kt < 10; ++kt) {
        const int curb = (kt & 1) * 8192;
        float4 a0, b0, a1, b1;
        if (kt < 8) STAGE_LOAD(kt + 2, a0, b0, a1, b1);
        MHALF(qacc, PE, PO, WqFb, curb, 64, 0, 0, kt, 1, 1);
        MHALF(qacc, PO, PE, WqFb, curb, 64, 0, 1, kt + 1, 0, kt < 9);
        __syncthreads();
        if (kt < 8) STAGE_WRITE(kt & 1, a0, b0, a1, b1);
    }
    // last __syncthreads (kt=9) = toks-dead barrier

    // ---- write Q f16 into per-wave [128][80] region (aliases token dbuf) ----
    const int qoff = w * 10240;
#pragma unroll
    for (int mi = 0; mi < 8; ++mi)
#pragma unroll
        for (int ni = 0; ni < 5; ++ni)
#pragma unroll
            for (int r = 0; r < 4; ++r)
                lds[qoff + (mi*16 + lhi*4 + r)*80 + ni*16 + l15] = f2h(qacc[mi][ni][r]);
    __builtin_amdgcn_sched_barrier(0);

    const f16x8 zf = {};
    // ---- S = Q K^T (packed K frags, kk-level prefetch) ----
    f32x4 sa[8][5] = {};
#define ATT_KK(ACC, PC, PN, FB, KK, NKK, DOPF) do { \
    if (DOPF) { \
        _Pragma("unroll") for (int f = 0; f < 5; ++f) \
            (PN)[f] = *(const f16x8*)((FB) + (f * 3 + (NKK)) * 512 + lane * 8); \
    } \
    const int kcol = ((KK) < 2) ? ((KK)*32 + lhi*8) : (64 + (lhi & 1)*8); \
    PRIO1(); \
    _Pragma("unroll") for (int mi = 0; mi < 8; ++mi) { \
        f16x8 aq_ = *(const f16x8*)&lds[qoff + (mi*16 + l15)*80 + kcol]; \
        if ((KK) == 2 && lhi >= 2) aq_ = zf; \
        _Pragma("unroll") for (int ni = 0; ni < 5; ++ni) \
            (ACC)[mi][ni] = __builtin_amdgcn_mfma_f32_16x16x32_f16(aq_, (PC)[ni], (ACC)[mi][ni], 0, 0, 0); \
    } \
    PRIO0(); \
} while (0)

#pragma unroll
    for (int f = 0; f < 5; ++f)
        PE[f] = *(const f16x8*)(KFb + (f * 3) * 512 + lane * 8);
    ATT_KK(sa, PE, PO, KFb, 0, 1, 1);
    ATT_KK(sa, PO, PE, KFb, 1, 2, 1);
    ATT_KK(sa, PE, PO, KFb, 2, 0, 0);
    __builtin_amdgcn_sched_barrier(0);

    // ---- softmax over s (77 valid), P f16 back into the same region ----
    const float sc = 0.11180339887498949f;   // 1/sqrt(80)
#pragma unroll
    for (int mi = 0; mi < 8; ++mi)
#pragma unroll
        for (int r = 0; r < 4; ++r) {
            float v0 = sa[mi][0][r]*sc, v1 = sa[mi][1][r]*sc, v2 = sa[mi][2][r]*sc,
                  v3 = sa[mi][3][r]*sc, v4 = sa[mi][4][r]*sc;
            bool ok4 = l15 < 13;             // col 64+l15 < 77
            float mx = fmaxf(fmaxf(v0, v1), fmaxf(v2, v3));
            if (ok4) mx = fmaxf(mx, v4);
#pragma unroll
            for (int off = 1; off < 16; off <<= 1) mx = fmaxf(mx, __shfl_xor(mx, off, 16));
            float p0 = __expf(v0-mx), p1 = __expf(v1-mx), p2 = __expf(v2-mx), p3 = __expf(v3-mx);
            float p4 = ok4 ? __expf(v4-mx) : 0.f;
            float sm = p0+p1+p2+p3+p4;
#pragma unroll
            for (int off = 1; off < 16; off <<= 1) sm += __shfl_xor(sm, off, 16);
            float inv = 1.f / sm;
            int row = mi*16 + lhi*4 + r;
            lds[qoff + row*80 + 0*16 + l15] = f2h(p0*inv);
            lds[qoff + row*80 + 1*16 + l15] = f2h(p1*inv);
            lds[qoff + row*80 + 2*16 + l15] = f2h(p2*inv);
            lds[qoff + row*80 + 3*16 + l15] = f2h(p3*inv);
            lds[qoff + row*80 + 4*16 + l15] = f2h(p4*inv);
        }
    __builtin_amdgcn_sched_barrier(0);

    // ---- O = P V (packed V frags; s>=77 cols are true zeros) ----
    f32x4 oa[8][5] = {};
#pragma unroll
    for (int f = 0; f < 5; ++f)
        PE[f] = *(const f16x8*)(VFb + (f * 3) * 512 + lane * 8);
    ATT_KK(oa, PE, PO, VFb, 0, 1, 1);
    ATT_KK(oa, PO, PE, VFb, 1, 2, 1);
    ATT_KK(oa, PE, PO, VFb, 2, 0, 0);
#undef ATT_KK
    __syncthreads();                      // Q/P regions dead everywhere

    // ---- ctxall [128][640] swizzled = concat of heads ----
#pragma unroll
    for (int mi = 0; mi < 8; ++mi)
#pragma unroll
        for (int ni = 0; ni < 5; ++ni)
#pragma unroll
            for (int r = 0; r < 4; ++r) {
                int row = mi*16 + lhi*4 + r;
                int col = w*80 + ni*16 + l15;
                int slot = col >> 3;
                int phys = (slot & ~7) | ((slot ^ row) & 7);
                lds[row*640 + phys*8 + (col & 7)] = f2h(oa[mi][ni][r]);
            }
    __syncthreads();                      // ctxall ready

    // ---- O projection (barrier-free): out = ctxall @ Wo + bo ----
    f32x4 cacc[8][5] = {};
#pragma unroll
    for (int f = 0; f < 5; ++f)
        PE[f] = *(const f16x8*)(WoFb + (f * 2) * 512 + lane * 8);
    for (int kt = 0; kt < 10; ++kt) {
        MHALF(cacc, PE, PO, WoFb, 0, 640, kt * 8, 0, kt, 1, 1);
        MHALF(cacc, PO, PE, WoFb, 0, 640, kt * 8, 1, kt + 1, 0, kt < 9);
    }
#undef MHALF

    // ---- epilogue: f32 out + bias ----
#pragma unroll
    for (int ni = 0; ni < 5; ++ni) {
        int col = w*80 + ni*16 + l15;
        float bvl = bo[col];
#pragma unroll
        for (int mi = 0; mi < 8; ++mi)
#pragma unroll
            for (int r = 0; r < 4; ++r)
                out[(rowbase + mi*16 + lhi*4 + r) * 640 + col] = cacc[mi][ni][r] + bvl;
    }
#undef STAGE_LOAD
#undef STAGE_WRITE
}

extern "C" void kernel_launch(void* const* d_in, const int* in_sizes, int n_in,
                              void* d_out, int out_size, void* d_ws, size_t ws_size,
                              hipStream_t stream) {
    (void)in_sizes; (void)n_in; (void)out_size; (void)ws_size;
    const float* tokens  = (const float*)d_in[0];
    const float* context = (const float*)d_in[1];
    const float* Wq = (const float*)d_in[2];
    const float* Wk = (const float*)d_in[3];
    const float* Wv = (const float*)d_in[4];
    const float* Wo = (const float*)d_in[5];
    const float* bo = (const float*)d_in[6];
    float* out = (float*)d_out;

    ushort* ws   = (ushort*)d_ws;
    ushort* ctx16 = ws;                                   // 616*768
    ushort* WkvT = ctx16 + (size_t)616 * 768;             // 1280*768
    ushort* KVb  = WkvT + (size_t)1280 * 768;             // 616*1280
    ushort* WqF  = KVb  + (size_t)616 * 1280;             // 640*640
    ushort* WoF  = WqF  + (size_t)640 * 640;              // 640*640
    ushort* KF   = WoF  + (size_t)640 * 640;              // 61440*8
    ushort* VF   = KF   + (size_t)61440 * 8;              // 61440*8

    cvt_kernel<<<462, 256, 0, stream>>>(context, ctx16, 616 * 768 / 4);
    transpose_cvt2<<<dim3(20, 24, 2), dim3(32, 8), 0, stream>>>(Wk, Wv, WkvT);
    pack_wfrag<<<200, 256, 0, stream>>>(Wq, WqF);
    pack_wfrag<<<200, 256, 0, stream>>>(Wo, WoF);
    gemm_bt<1, 0><<<dim3(5, 10), 256, 0, stream>>>(ctx16, WkvT, KVb, nullptr, 616, 1280, 768);
    pack_kvfrag<<<240, 256, 0, stream>>>(KVb, KF, VF);
    fused_attn<<<dim3(32, 8), 512, 0, stream>>>(tokens, WqF, KF, VF, WoF, bo, out);
}

// Round 12
// 117.989 us; speedup vs baseline: 1.1004x; 1.0041x over previous
//
#include <hip/hip_runtime.h>
#include <hip/hip_bf16.h>
#include <hip/hip_fp16.h>

typedef __attribute__((ext_vector_type(4))) float f32x4;
typedef __attribute__((ext_vector_type(8))) _Float16 f16x8;
typedef __attribute__((ext_vector_type(8))) unsigned short u16x8;

__device__ __forceinline__ unsigned short f2h(float f) {
    _Float16 h = (_Float16)f;
    return __builtin_bit_cast(unsigned short, h);
}

#define GLOAD_LDS16(gp, lp) __builtin_amdgcn_global_load_lds( \
    (const __attribute__((address_space(1))) void*)(gp), \
    (__attribute__((address_space(3))) void*)(lp), 16, 0, 0)
#define PRIO1() __builtin_amdgcn_s_setprio(1)
#define PRIO0() __builtin_amdgcn_s_setprio(0)

// ---------------- fp32 -> fp16 elementwise convert (vectorized) ----------------
__global__ void cvt_kernel(const float* __restrict__ in, ushort* __restrict__ out, int n4) {
    int stride = gridDim.x * blockDim.x;
    for (int i = blockIdx.x * blockDim.x + threadIdx.x; i < n4; i += stride) {
        float4 v = ((const float4*)in)[i];
        ushort4 o;
        o.x = f2h(v.x); o.y = f2h(v.y); o.z = f2h(v.z); o.w = f2h(v.w);
        ((ushort4*)out)[i] = o;
    }
}

// ---------------- transpose + convert Wk/Wv (for the KV projection GEMM) ----------------
__global__ void transpose_cvt2(const float* __restrict__ Wk, const float* __restrict__ Wv,
                               ushort* __restrict__ WkvT) {
    __shared__ float tile[32][33];
    const int z = blockIdx.z;
    const float* src = z ? Wv : Wk;
    ushort* dst = WkvT + (size_t)z * 640 * 768;
    const int R = 768, C = 640;
    int tx = threadIdx.x, ty = threadIdx.y;
    int c = blockIdx.x * 32 + tx;
    int r0 = blockIdx.y * 32;
#pragma unroll
    for (int i = ty; i < 32; i += 8) {
        int r = r0 + i;
        tile[i][tx] = (r < R && c < C) ? src[(size_t)r * C + c] : 0.f;
    }
    __syncthreads();
    int rr = r0 + tx;
    int c0 = blockIdx.x * 32;
#pragma unroll
    for (int i = ty; i < 32; i += 8) {
        int cc = c0 + i;
        if (cc < C && rr < R) dst[(size_t)cc * R + rr] = f2h(tile[tx][i]);
    }
}

// ---------------- pack W (fp32 [640 k][640 n]) into fragment-linear f16 ----------------
__global__ void pack_wfrag(const float* __restrict__ W, ushort* __restrict__ WF) {
    int g = blockIdx.x * 256 + threadIdx.x;   // 0 .. 51199
    if (g >= 51200) return;
    int lane = g & 63;
    int fi = (g >> 6) % 10;
    int kt = ((g >> 6) / 10) % 10;
    int h  = (g >> 6) / 100;
    int ni = fi >> 1, kk = fi & 1;
    int n  = h * 80 + ni * 16 + (lane & 15);
    int k0 = kt * 64 + kk * 32 + (lane >> 4) * 8;
    u16x8 o;
#pragma unroll
    for (int e = 0; e < 8; ++e) o[e] = f2h(W[(size_t)(k0 + e) * 640 + n]);
    *(u16x8*)&WF[(size_t)g * 8] = o;
}

// ---------------- pack K,V fragments from KVb ----------------
__global__ void pack_kvfrag(const ushort* __restrict__ KVb,
                            ushort* __restrict__ KF, ushort* __restrict__ VF) {
    int g = blockIdx.x * 256 + threadIdx.x;   // 0 .. 61439
    if (g >= 61440) return;
    int lane = g & 63;
    int fi = (g >> 6) % 15;
    int bh = (g >> 6) / 15;
    int b = bh >> 3, h = bh & 7;
    int ni = fi / 3, kk = fi % 3;
    int l15 = lane & 15, lhi = lane >> 4;
    int sr = ni * 16 + l15; if (sr > 76) sr = 76;
    int d0 = kk * 32 + lhi * 8;
    u16x8 ko, vo;
#pragma unroll
    for (int e = 0; e < 8; ++e)
        ko[e] = KVb[((size_t)b * 77 + sr) * 1280 + h * 80 + d0 + e];
    int dv = ni * 16 + l15;            // < 80 always
    int s0 = kk * 32 + lhi * 8;
#pragma unroll
    for (int e = 0; e < 8; ++e) {
        int s = s0 + e;
        vo[e] = (s < 77) ? KVb[((size_t)b * 77 + s) * 1280 + 640 + h * 80 + dv] : (ushort)0;
    }
    *(u16x8*)&KF[(size_t)g * 8] = ko;
    *(u16x8*)&VF[(size_t)g * 8] = vo;
}

// ---------------- 128x128 GEMM (for the tiny KV projection) ----------------
template<int OUT_F16, int HAS_BIAS>
__global__ __launch_bounds__(256) void gemm_bt(
    const ushort* __restrict__ A, const ushort* __restrict__ Bt,
    void* __restrict__ C, const float* __restrict__ bias,
    int M, int N, int K)
{
    __shared__ ushort As[128 * 64];
    __shared__ ushort Bs[128 * 64];
    const int tid = threadIdx.x;
    const int lane = tid & 63;
    const int w = tid >> 6;
    const int wr = (w >> 1) * 64, wc = (w & 1) * 64;
    const int m0 = blockIdx.x * 128, n0 = blockIdx.y * 128;
    const int l15 = lane & 15, lhi = lane >> 4;

    f32x4 acc[4][4] = {};

    for (int k0 = 0; k0 < K; k0 += 64) {
        __syncthreads();
#pragma unroll
        for (int i = 0; i < 4; ++i) {
            int c = i * 256 + tid;
            int m = m0 + (c >> 3);
            if (m > M - 1) m = M - 1;
            GLOAD_LDS16(A + (size_t)m * K + k0 + (c & 7) * 8, &As[c * 8]);
        }
#pragma unroll
        for (int i = 0; i < 4; ++i) {
            int c = i * 256 + tid;
            GLOAD_LDS16(Bt + (size_t)(n0 + (c >> 3)) * K + k0 + (c & 7) * 8, &Bs[c * 8]);
        }
        __syncthreads();
#pragma unroll
        for (int kk = 0; kk < 2; ++kk) {
            f16x8 af[4], bfr[4];
#pragma unroll
            for (int mi = 0; mi < 4; ++mi)
                af[mi] = *(const f16x8*)&As[(wr + mi * 16 + l15) * 64 + kk * 32 + lhi * 8];
#pragma unroll
            for (int ni = 0; ni < 4; ++ni)
                bfr[ni] = *(const f16x8*)&Bs[(wc + ni * 16 + l15) * 64 + kk * 32 + lhi * 8];
#pragma unroll
            for (int mi = 0; mi < 4; ++mi)
#pragma unroll
                for (int ni = 0; ni < 4; ++ni)
                    acc[mi][ni] = __builtin_amdgcn_mfma_f32_16x16x32_f16(
                        af[mi], bfr[ni], acc[mi][ni], 0, 0, 0);
        }
    }

#pragma unroll
    for (int mi = 0; mi < 4; ++mi)
#pragma unroll
        for (int ni = 0; ni < 4; ++ni)
#pragma unroll
            for (int r = 0; r < 4; ++r) {
                int row = m0 + wr + mi * 16 + lhi * 4 + r;
                int col = n0 + wc + ni * 16 + l15;
                if (row < M) {
                    float v = acc[mi][ni][r];
                    if (HAS_BIAS) v += bias[col];
                    if (OUT_F16) ((ushort*)C)[(size_t)row * N + col] = f2h(v);
                    else         ((float*)C)[(size_t)row * N + col] = v;
                }
            }
}

// ================= fused: tokens->Q-proj->attention->O-proj->out =================
// R12 = R11 (128-row blocks, 256 blocks = 1/CU, best W-amortization) with the spill
// fixed: ONE f32x4 acc[8][5] reused across Q-proj/QK^T/PV/O-proj (R11's four distinct
// 160-reg arrays defeated the allocator's liveness merging across phase boundaries ->
// 40 MB scratch writes). Re-zeroed explicitly between phases. launch_bounds(512) only
// (no wave cap) so the allocator may exceed 128 arch VGPRs if needed.
// LDS 160 KiB: token dbuf [2][128][64] @0/8192; per-wave Q/P [128][80] @ w*10240;
//   ctxall [128][640] swizzled @0 (sequential aliasing with barriers).
__global__ __launch_bounds__(512) void fused_attn(
    const float* __restrict__ tokens, const ushort* __restrict__ WqF,
    const ushort* __restrict__ KF, const ushort* __restrict__ VF,
    const ushort* __restrict__ WoF, const float* __restrict__ bo,
    float* __restrict__ out)
{
    __shared__ __align__(16) ushort lds[81920];   // 160 KiB
    const int tid = threadIdx.x;
    const int lane = tid & 63;
    const int w = tid >> 6;
    const int l15 = lane & 15, lhi = lane >> 4;
    const int tt = blockIdx.x, b = blockIdx.y;
    const size_t rowbase = (size_t)b * 4096 + (size_t)tt * 128;

    const ushort* WqFb = WqF + (size_t)w * 10 * 5120;
    const ushort* WoFb = WoF + (size_t)w * 10 * 5120;
    const ushort* KFb  = KF + (size_t)(b * 8 + w) * 15 * 512;
    const ushort* VFb  = VF + (size_t)(b * 8 + w) * 15 * 512;

    // staging map: entries e = tid and tid+512 of 1024 (row = e>>3, 16B slot = e&7)
    const int r0s = tid >> 3;             // 0..63
    const int r1s = r0s + 64;             // 64..127
    const int s0s = tid & 7;
    const int d0s = r0s * 64 + (s0s ^ (r0s & 7)) * 8;   // swizzled dest (ushorts)
    const int d1s = r1s * 64 + (s0s ^ (r1s & 7)) * 8;

#define STAGE_LOAD(C, A0, B0, A1, B1) do { \
    const float* p0_ = tokens + (rowbase + r0s) * 640 + (C) * 64 + s0s * 8; \
    const float* p1_ = tokens + (rowbase + r1s) * 640 + (C) * 64 + s0s * 8; \
    A0 = ((const float4*)p0_)[0]; B0 = ((const float4*)p0_)[1]; \
    A1 = ((const float4*)p1_)[0]; B1 = ((const float4*)p1_)[1]; \
} while (0)
#define STAGE_WRITE(BUF, A0, B0, A1, B1) do { \
    u16x8 o0_, o1_; \
    o0_[0]=f2h(A0.x); o0_[1]=f2h(A0.y); o0_[2]=f2h(A0.z); o0_[3]=f2h(A0.w); \
    o0_[4]=f2h(B0.x); o0_[5]=f2h(B0.y); o0_[6]=f2h(B0.z); o0_[7]=f2h(B0.w); \
    o1_[0]=f2h(A1.x); o1_[1]=f2h(A1.y); o1_[2]=f2h(A1.z); o1_[3]=f2h(A1.w); \
    o1_[4]=f2h(B1.x); o1_[5]=f2h(B1.y); o1_[6]=f2h(B1.z); o1_[7]=f2h(B1.w); \
    *(u16x8*)&lds[(BUF) * 8192 + d0s] = o0_; \
    *(u16x8*)&lds[(BUF) * 8192 + d1s] = o1_; \
} while (0)

    // ---- prologue: stage chunks 0,1 ----
    {
        float4 a0, b0, a1, b1, c0, d0, c1, d1;
        STAGE_LOAD(0, a0, b0, a1, b1);
        STAGE_LOAD(1, c0, d0, c1, d1);
        STAGE_WRITE(0, a0, b0, a1, b1);
        STAGE_WRITE(1, c0, d0, c1, d1);
    }
    f16x8 PE[5], PO[5];
#pragma unroll
    for (int f = 0; f < 5; ++f)
        PE[f] = *(const f16x8*)(WqFb + (f * 2) * 512 + lane * 8);
    __syncthreads();

    // ---- ONE accumulator, reused across all 4 matmul phases ----
    f32x4 acc[8][5];
#define ZACC() do { \
    _Pragma("unroll") for (int i_ = 0; i_ < 8; ++i_) \
    _Pragma("unroll") for (int j_ = 0; j_ < 5; ++j_) \
        acc[i_][j_] = (f32x4){0.f, 0.f, 0.f, 0.f}; \
} while (0)

// one kk-half: optional prefetch of next half's 5 B-frags; 8 A-frags read singly
#define MHALF(PC, PN, WB, CURB, RSTR, SBASE, KK, NKT, NKK, DOPF) do { \
    if (DOPF) { \
        _Pragma("unroll") for (int f = 0; f < 5; ++f) \
            (PN)[f] = *(const f16x8*)((WB) + (size_t)(NKT) * 5120 + (f * 2 + (NKK)) * 512 + lane * 8); \
    } \
    PRIO1(); \
    _Pragma("unroll") for (int mi = 0; mi < 8; ++mi) { \
        int row_ = mi * 16 + l15; \
        f16x8 a_ = *(const f16x8*)&lds[(CURB) + row_ * (RSTR) + ((SBASE) + (((KK) * 4 + lhi) ^ (row_ & 7))) * 8]; \
        _Pragma("unroll") for (int ni = 0; ni < 5; ++ni) \
            acc[mi][ni] = __builtin_amdgcn_mfma_f32_16x16x32_f16(a_, (PC)[ni], acc[mi][ni], 0, 0, 0); \
    } \
    PRIO0(); \
} while (0)

    // ---- Q projection: acc = toks(128x640) @ Wq[:, w*80..+80] ----
    ZACC();
    for (int kt = 0; kt < 10; ++kt) {
        const int curb = (kt & 1) * 8192;
        float4 a0, b0, a1, b1;
        if (kt < 8) STAGE_LOAD(kt + 2, a0, b0, a1, b1);
        MHALF(PE, PO, WqFb, curb, 64, 0, 0, kt, 1, 1);
        MHALF(PO, PE, WqFb, curb, 64, 0, 1, kt + 1, 0, kt < 9);
        __syncthreads();
        if (kt < 8) STAGE_WRITE(kt & 1, a0, b0, a1, b1);
    }
    // last __syncthreads (kt=9) = toks-dead barrier

    // ---- write Q f16 into per-wave [128][80] region (aliases token dbuf) ----
    const int qoff = w * 10240;
#pragma unroll
    for (int mi = 0; mi < 8; ++mi)
#pragma unroll
        for (int ni = 0; ni < 5; ++ni)
#pragma unroll
            for (int r = 0; r < 4; ++r)
                lds[qoff + (mi*16 + lhi*4 + r)*80 + ni*16 + l15] = f2h(acc[mi][ni][r]);
    __builtin_amdgcn_sched_barrier(0);

    const f16x8 zf = {};
    // ---- S = Q K^T (packed K frags, kk-level prefetch) ----
#define ATT_KK(PC, PN, FB, KK, NKK, DOPF) do { \
    if (DOPF) { \
        _Pragma("unroll") for (int f = 0; f < 5; ++f) \
            (PN)[f] = *(const f16x8*)((FB) + (f * 3 + (NKK)) * 512 + lane * 8); \
    } \
    const int kcol = ((KK) < 2) ? ((KK)*32 + lhi*8) : (64 + (lhi & 1)*8); \
    PRIO1(); \
    _Pragma("unroll") for (int mi = 0; mi < 8; ++mi) { \
        f16x8 aq_ = *(const f16x8*)&lds[qoff + (mi*16 + l15)*80 + kcol]; \
        if ((KK) == 2 && lhi >= 2) aq_ = zf; \
        _Pragma("unroll") for (int ni = 0; ni < 5; ++ni) \
            acc[mi][ni] = __builtin_amdgcn_mfma_f32_16x16x32_f16(aq_, (PC)[ni], acc[mi][ni], 0, 0, 0); \
    } \
    PRIO0(); \
} while (0)

    ZACC();
#pragma unroll
    for (int f = 0; f < 5; ++f)
        PE[f] = *(const f16x8*)(KFb + (f * 3) * 512 + lane * 8);
    ATT_KK(PE, PO, KFb, 0, 1, 1);
    ATT_KK(PO, PE, KFb, 1, 2, 1);
    ATT_KK(PE, PO, KFb, 2, 0, 0);
    __builtin_amdgcn_sched_barrier(0);

    // ---- softmax over s (77 valid), P f16 back into the same region ----
    const float sc = 0.11180339887498949f;   // 1/sqrt(80)
#pragma unroll
    for (int mi = 0; mi < 8; ++mi)
#pragma unroll
        for (int r = 0; r < 4; ++r) {
            float v0 = acc[mi][0][r]*sc, v1 = acc[mi][1][r]*sc, v2 = acc[mi][2][r]*sc,
                  v3 = acc[mi][3][r]*sc, v4 = acc[mi][4][r]*sc;
            bool ok4 = l15 < 13;             // col 64+l15 < 77
            float mx = fmaxf(fmaxf(v0, v1), fmaxf(v2, v3));
            if (ok4) mx = fmaxf(mx, v4);
#pragma unroll
            for (int off = 1; off < 16; off <<= 1) mx = fmaxf(mx, __shfl_xor(mx, off, 16));
            float p0 = __expf(v0-mx), p1 = __expf(v1-mx), p2 = __expf(v2-mx), p3 = __expf(v3-mx);
            float p4 = ok4 ? __expf(v4-mx) : 0.f;
            float sm = p0+p1+p2+p3+p4;
#pragma unroll
            for (int off = 1; off < 16; off <<= 1) sm += __shfl_xor(sm, off, 16);
            float inv = 1.f / sm;
            int row = mi*16 + lhi*4 + r;
            lds[qoff + row*80 + 0*16 + l15] = f2h(p0*inv);
            lds[qoff + row*80 + 1*16 + l15] = f2h(p1*inv);
            lds[qoff + row*80 + 2*16 + l15] = f2h(p2*inv);
            lds[qoff + row*80 + 3*16 + l15] = f2h(p3*inv);
            lds[qoff + row*80 + 4*16 + l15] = f2h(p4*inv);
        }
    __builtin_amdgcn_sched_barrier(0);

    // ---- O = P V (packed V frags; s>=77 cols are true zeros) ----
    ZACC();
#pragma unroll
    for (int f = 0; f < 5; ++f)
        PE[f] = *(const f16x8*)(VFb + (f * 3) * 512 + lane * 8);
    ATT_KK(PE, PO, VFb, 0, 1, 1);
    ATT_KK(PO, PE, VFb, 1, 2, 1);
    ATT_KK(PE, PO, VFb, 2, 0, 0);
#undef ATT_KK
    __syncthreads();                      // Q/P regions dead everywhere

    // ---- ctxall [128][640] swizzled = concat of heads ----
#pragma unroll
    for (int mi = 0; mi < 8; ++mi)
#pragma unroll
        for (int ni = 0; ni < 5; ++ni)
#pragma unroll
            for (int r = 0; r < 4; ++r) {
                int row = mi*16 + lhi*4 + r;
                int col = w*80 + ni*16 + l15;
                int slot = col >> 3;
                int phys = (slot & ~7) | ((slot ^ row) & 7);
                lds[row*640 + phys*8 + (col & 7)] = f2h(acc[mi][ni][r]);
            }
    __syncthreads();                      // ctxall ready

    // ---- O projection (barrier-free): out = ctxall @ Wo + bo ----
    ZACC();
#pragma unroll
    for (int f = 0; f < 5; ++f)
        PE[f] = *(const f16x8*)(WoFb + (f * 2) * 512 + lane * 8);
    for (int kt = 0; kt < 10; ++kt) {
        MHALF(PE, PO, WoFb, 0, 640, kt * 8, 0, kt, 1, 1);
        MHALF(PO, PE, WoFb, 0, 640, kt * 8, 1, kt + 1, 0, kt < 9);
    }
#undef MHALF
#undef ZACC

    // ---- epilogue: f32 out + bias ----
#pragma unroll
    for (int ni = 0; ni < 5; ++ni) {
        int col = w*80 + ni*16 + l15;
        float bvl = bo[col];
#pragma unroll
        for (int mi = 0; mi < 8; ++mi)
#pragma unroll
            for (int r = 0; r < 4; ++r)
                out[(rowbase + mi*16 + lhi*4 + r) * 640 + col] = acc[mi][ni][r] + bvl;
    }
#undef STAGE_LOAD
#undef STAGE_WRITE
}

extern "C" void kernel_launch(void* const* d_in, const int* in_sizes, int n_in,
                              void* d_out, int out_size, void* d_ws, size_t ws_size,
                              hipStream_t stream) {
    (void)in_sizes; (void)n_in; (void)out_size; (void)ws_size;
    const float* tokens  = (const float*)d_in[0];
    const float* context = (const float*)d_in[1];
    const float* Wq = (const float*)d_in[2];
    const float* Wk = (const float*)d_in[3];
    const float* Wv = (const float*)d_in[4];
    const float* Wo = (const float*)d_in[5];
    const float* bo = (const float*)d_in[6];
    float* out = (float*)d_out;

    ushort* ws   = (ushort*)d_ws;
    ushort* ctx16 = ws;                                   // 616*768
    ushort* WkvT = ctx16 + (size_t)616 * 768;             // 1280*768
    ushort* KVb  = WkvT + (size_t)1280 * 768;             // 616*1280
    ushort* WqF  = KVb  + (size_t)616 * 1280;             // 640*640
    ushort* WoF  = WqF  + (size_t)640 * 640;              // 640*640
    ushort* KF   = WoF  + (size_t)640 * 640;              // 61440*8
    ushort* VF   = KF   + (size_t)61440 * 8;              // 61440*8

    cvt_kernel<<<462, 256, 0, stream>>>(context, ctx16, 616 * 768 / 4);
    transpose_cvt2<<<dim3(20, 24, 2), dim3(32, 8), 0, stream>>>(Wk, Wv, WkvT);
    pack_wfrag<<<200, 256, 0, stream>>>(Wq, WqF);
    pack_wfrag<<<200, 256, 0, stream>>>(Wo, WoF);
    gemm_bt<1, 0><<<dim3(5, 10), 256, 0, stream>>>(ctx16, WkvT, KVb, nullptr, 616, 1280, 768);
    pack_kvfrag<<<240, 256, 0, stream>>>(KVb, KF, VF);
    fused_attn<<<dim3(32, 8), 512, 0, stream>>>(tokens, WqF, KF, VF, WoF, bo, out);
}